// Round 1
// baseline (189.867 us; speedup 1.0000x reference)
//
#include <hip/hip_runtime.h>

// ============================================================================
// einsum('bcshw,ijkl->bklhw') has no shared labels => full factorization:
//   out[b, kl, hw] = S_x[b,hw] * S_C[kl]
//   S_x[b,h,w] = sum_{p1,p2,ch} x[b, p1*8+h, p2*8+w, ch]
//   S_C[kl]    = sum over 3072 rows of C viewed as [3072][1024]
//
// 2 dispatches, no memset, no atomics (every ws word written before read):
//   K1: block-private partials. Blocks 0..15: C column-sums, 192 rows each
//       (heavy, scheduled first so they overlap the x-phase). Blocks 16..1039:
//       x-chunks, one (image, 32-row slab) each, float4 loads.
//   K2: finalize partials in-LDS + outer-product expand, float4 stores.
// ============================================================================

__global__ __launch_bounds__(192) void reduce_partials(
    const float4* __restrict__ x4,   // [128*256 rows][192 f4]
    const float4* __restrict__ C4,   // [3072 rows][256 f4]
    float*  __restrict__ cpart,      // [16][1024]
    float*  __restrict__ xpart)      // [1024][64]
{
    const int t   = threadIdx.x;
    const int blk = blockIdx.x;

    if (blk < 16) {
        // ---- C partial: rows blk*192 .. +192, coalesced f4 column sums ----
        const size_t r0 = (size_t)blk * 192;
        for (int c4 = t; c4 < 256; c4 += 192) {
            const float4* p = C4 + r0 * 256 + c4;
            float ax = 0, ay = 0, az = 0, aw = 0;
            float bx = 0, by = 0, bz = 0, bw = 0;
#pragma unroll 4
            for (int r = 0; r < 192; r += 2) {
                float4 v0 = p[0];
                float4 v1 = p[256];
                ax += v0.x; ay += v0.y; az += v0.z; aw += v0.w;
                bx += v1.x; by += v1.y; bz += v1.z; bw += v1.w;
                p += 512;
            }
            float4 s;
            s.x = ax + bx; s.y = ay + by; s.z = az + bz; s.w = aw + bw;
            ((float4*)cpart)[blk * 256 + c4] = s;
        }
        return;
    }

    // ---- x partial: image b, rows y0..y0+32, float4 loads ----
    // Row = 768 floats = 192 f4. Thread t reads f4 #t of each row; its 4
    // elements are positions p = 4t+e. Threads t, t+48, t+96, t+144 share
    // p mod 24 (192 % 24 == 0), i.e. the same (w, ch) class.
    const int xb    = blk - 16;
    const int b     = xb >> 3;
    const int chunk = xb & 7;
    const float4* base = x4 + ((size_t)b * 256 + (size_t)chunk * 32) * 192 + t;

    float4 acc[8];
#pragma unroll
    for (int h = 0; h < 8; ++h) { acc[h].x = acc[h].y = acc[h].z = acc[h].w = 0.f; }

#pragma unroll
    for (int h = 0; h < 8; ++h) {
#pragma unroll
        for (int j = 0; j < 4; ++j) {    // rows chunk*32 + h + 8j, all y%8 == h
            float4 v = base[(size_t)(h + 8 * j) * 192];
            acc[h].x += v.x; acc[h].y += v.y; acc[h].z += v.z; acc[h].w += v.w;
        }
    }

    __shared__ float4 ldsv[192][9];   // [t][h]; 9 (not 8) spreads write banks
    __shared__ float  plane[8][193];  // [h][pos mod 192]; 193 breaks conflicts
#pragma unroll
    for (int h = 0; h < 8; ++h) ldsv[t][h] = acc[h];
    __syncthreads();

    {   // stage 2: fold the 4 period-groups -> per-class column sums
        const int h2  = t / 48;           // 0..3
        const int tau = t - h2 * 48;      // 0..47
#pragma unroll
        for (int k = 0; k < 2; ++k) {
            const int hh = h2 + 4 * k;
            float4 s0 = ldsv[tau      ][hh];
            float4 s1 = ldsv[tau +  48][hh];
            float4 s2 = ldsv[tau +  96][hh];
            float4 s3 = ldsv[tau + 144][hh];
            plane[hh][4 * tau + 0] = s0.x + s1.x + s2.x + s3.x;
            plane[hh][4 * tau + 1] = s0.y + s1.y + s2.y + s3.y;
            plane[hh][4 * tau + 2] = s0.z + s1.z + s2.z + s3.z;
            plane[hh][4 * tau + 3] = s0.w + s1.w + s2.w + s3.w;
        }
    }
    __syncthreads();

    if (t < 64) {   // bin (h,w): positions p' = 24g + 3w + c, g<8, c<3
        const int h = t >> 3, w = t & 7;
        float s = 0.f;
#pragma unroll
        for (int g = 0; g < 8; ++g) {
            const float* pp = &plane[h][24 * g + 3 * w];
            s += pp[0] + pp[1] + pp[2];
        }
        xpart[xb * 64 + t] = s;   // bin == t == h*8+w
    }
}

// K2: finalize sx (8-deep) + sC slice (16-deep) in LDS, then expand.
// grid (8, 128): block = (kl-chunk of 128, image b). 2048 f4 stores/block.
__global__ __launch_bounds__(256) void finalize_expand(
    const float* __restrict__ xpart,   // [1024][64]
    const float* __restrict__ cpart,   // [16][1024]
    float4* __restrict__ out4)         // [128][1024][16]
{
    const int t   = threadIdx.x;
    const int klc = blockIdx.x;   // [0,8)
    const int b   = blockIdx.y;   // [0,128)

    __shared__ float4 sxv[16];    // sx[b][0..63] as 16 f4
    __shared__ float  scl[128];   // sC[klc*128 .. +128]

    if (t < 64) {
        float s = 0.f;
#pragma unroll
        for (int j = 0; j < 8; ++j) s += xpart[((b << 3) + j) * 64 + t];
        ((float*)sxv)[t] = s;
    } else if (t < 192) {
        const int c = klc * 128 + (t - 64);
        float s = 0.f;
#pragma unroll
        for (int g = 0; g < 16; ++g) s += cpart[g * 1024 + c];
        scl[t - 64] = s;
    }
    __syncthreads();

    float4* ob = out4 + (size_t)b * 16384 + (size_t)klc * 2048;
#pragma unroll
    for (int k = 0; k < 8; ++k) {
        const int idx = k * 256 + t;        // [0,2048)
        const float4 v = sxv[idx & 15];     // broadcast-friendly
        const float  s = scl[idx >> 4];
        float4 r;
        r.x = v.x * s; r.y = v.y * s; r.z = v.z * s; r.w = v.w * s;
        ob[idx] = r;
    }
}

extern "C" void kernel_launch(void* const* d_in, const int* in_sizes, int n_in,
                              void* d_out, int out_size, void* d_ws, size_t ws_size,
                              hipStream_t stream) {
    const float4* x4 = (const float4*)d_in[0];   // 128*256*256*3 floats
    const float4* C4 = (const float4*)d_in[1];   // 3072*1024 floats
    float* cpart = (float*)d_ws;                 // 16*1024 floats
    float* xpart = (float*)d_ws + 16384;         // 1024*64 floats

    reduce_partials<<<dim3(16 + 1024), 192, 0, stream>>>(x4, C4, cpart, xpart);
    finalize_expand<<<dim3(8, 128),    256, 0, stream>>>(xpart, cpart, (float4*)d_out);
}

// Round 2
// 172.170 us; speedup vs baseline: 1.1028x; 1.1028x over previous
//
#include <hip/hip_runtime.h>

// ============================================================================
// einsum('bcshw,ijkl->bklhw') has no shared labels => full factorization:
//   out[b, kl, hw] = S_x[b,hw] * S_C[kl]
//   S_x[b,h,w] = sum_{p1,p2,ch} x[b, p1*8+h, p2*8+w, ch]
//   S_C[kl]    = sum over 3072 rows of C viewed as [3072][1024]
//
// 2 dispatches, no memset, no atomics (every ws word written before read):
//   K1: blocks 0..95:  C column-sums, 32 rows each (96-way parallel so the
//       C-phase overlaps the x-phase instead of tailing on 16 CUs — the
//       Round-1 regression). Blocks 96..1119: x-chunks, one (image, 32-row
//       slab) each, float4 loads.
//   K2: finalize partials in-LDS + outer-product expand, float4 stores.
// ============================================================================

__global__ __launch_bounds__(192) void reduce_partials(
    const float4* __restrict__ x4,   // [128*256 rows][192 f4]
    const float4* __restrict__ C4,   // [3072 rows][256 f4]
    float*  __restrict__ cpart,      // [96][1024]
    float*  __restrict__ xpart)      // [1024][64]
{
    const int t   = threadIdx.x;
    const int blk = blockIdx.x;

    if (blk < 96) {
        // ---- C partial: rows blk*32 .. +32, coalesced f4 column sums ----
        const size_t r0 = (size_t)blk * 32;
        for (int c4 = t; c4 < 256; c4 += 192) {
            const float4* p = C4 + r0 * 256 + c4;
            float ax = 0, ay = 0, az = 0, aw = 0;
            float bx = 0, by = 0, bz = 0, bw = 0;
#pragma unroll
            for (int r = 0; r < 32; r += 2) {        // 32 independent loads
                float4 v0 = p[0];
                float4 v1 = p[256];
                ax += v0.x; ay += v0.y; az += v0.z; aw += v0.w;
                bx += v1.x; by += v1.y; bz += v1.z; bw += v1.w;
                p += 512;
            }
            float4 s;
            s.x = ax + bx; s.y = ay + by; s.z = az + bz; s.w = aw + bw;
            ((float4*)cpart)[blk * 256 + c4] = s;
        }
        return;
    }

    // ---- x partial: image b, rows y0..y0+32, float4 loads ----
    // Row = 768 floats = 192 f4. Thread t reads f4 #t of each row; its 4
    // elements are positions p = 4t+e. Threads t, t+48, t+96, t+144 share
    // p mod 24 (192 % 24 == 0), i.e. the same (w, ch) class.
    const int xb    = blk - 96;
    const int b     = xb >> 3;
    const int chunk = xb & 7;
    const float4* base = x4 + ((size_t)b * 256 + (size_t)chunk * 32) * 192 + t;

    float4 acc[8];
#pragma unroll
    for (int h = 0; h < 8; ++h) { acc[h].x = acc[h].y = acc[h].z = acc[h].w = 0.f; }

#pragma unroll
    for (int h = 0; h < 8; ++h) {
#pragma unroll
        for (int j = 0; j < 4; ++j) {    // rows chunk*32 + h + 8j, all y%8 == h
            float4 v = base[(size_t)(h + 8 * j) * 192];
            acc[h].x += v.x; acc[h].y += v.y; acc[h].z += v.z; acc[h].w += v.w;
        }
    }

    __shared__ float4 ldsv[192][9];   // [t][h]; 9 (not 8) spreads write banks
    __shared__ float  plane[8][193];  // [h][pos mod 192]; 193 breaks conflicts
#pragma unroll
    for (int h = 0; h < 8; ++h) ldsv[t][h] = acc[h];
    __syncthreads();

    {   // stage 2: fold the 4 period-groups -> per-class column sums
        const int h2  = t / 48;           // 0..3
        const int tau = t - h2 * 48;      // 0..47
#pragma unroll
        for (int k = 0; k < 2; ++k) {
            const int hh = h2 + 4 * k;
            float4 s0 = ldsv[tau      ][hh];
            float4 s1 = ldsv[tau +  48][hh];
            float4 s2 = ldsv[tau +  96][hh];
            float4 s3 = ldsv[tau + 144][hh];
            plane[hh][4 * tau + 0] = s0.x + s1.x + s2.x + s3.x;
            plane[hh][4 * tau + 1] = s0.y + s1.y + s2.y + s3.y;
            plane[hh][4 * tau + 2] = s0.z + s1.z + s2.z + s3.z;
            plane[hh][4 * tau + 3] = s0.w + s1.w + s2.w + s3.w;
        }
    }
    __syncthreads();

    if (t < 64) {   // bin (h,w): positions p' = 24g + 3w + c, g<8, c<3
        const int h = t >> 3, w = t & 7;
        float s = 0.f;
#pragma unroll
        for (int g = 0; g < 8; ++g) {
            const float* pp = &plane[h][24 * g + 3 * w];
            s += pp[0] + pp[1] + pp[2];
        }
        xpart[xb * 64 + t] = s;   // bin == t == h*8+w
    }
}

// K2: finalize sx (8-deep) + sC slice (96-deep) in LDS, then expand.
// grid (8, 128): block = (kl-chunk of 128, image b). 2048 f4 stores/block.
__global__ __launch_bounds__(256) void finalize_expand(
    const float* __restrict__ xpart,   // [1024][64]
    const float* __restrict__ cpart,   // [96][1024]
    float4* __restrict__ out4)         // [128][1024][16]
{
    const int t   = threadIdx.x;
    const int klc = blockIdx.x;   // [0,8)
    const int b   = blockIdx.y;   // [0,128)

    __shared__ float4 sxv[16];    // sx[b][0..63] as 16 f4
    __shared__ float  scl[128];   // sC[klc*128 .. +128]

    if (t < 64) {
        float s = 0.f;
#pragma unroll
        for (int j = 0; j < 8; ++j) s += xpart[((b << 3) + j) * 64 + t];
        ((float*)sxv)[t] = s;
    } else if (t < 192) {
        const int c = klc * 128 + (t - 64);
        float s = 0.f;
#pragma unroll 16
        for (int g = 0; g < 96; ++g) s += cpart[g * 1024 + c];
        scl[t - 64] = s;
    }
    __syncthreads();

    float4* ob = out4 + (size_t)b * 16384 + (size_t)klc * 2048;
#pragma unroll
    for (int k = 0; k < 8; ++k) {
        const int idx = k * 256 + t;        // [0,2048)
        const float4 v = sxv[idx & 15];     // broadcast-friendly
        const float  s = scl[idx >> 4];
        float4 r;
        r.x = v.x * s; r.y = v.y * s; r.z = v.z * s; r.w = v.w * s;
        ob[idx] = r;
    }
}

extern "C" void kernel_launch(void* const* d_in, const int* in_sizes, int n_in,
                              void* d_out, int out_size, void* d_ws, size_t ws_size,
                              hipStream_t stream) {
    const float4* x4 = (const float4*)d_in[0];   // 128*256*256*3 floats
    const float4* C4 = (const float4*)d_in[1];   // 3072*1024 floats
    float* cpart = (float*)d_ws;                 // 96*1024 floats
    float* xpart = (float*)d_ws + 96 * 1024;     // 1024*64 floats

    reduce_partials<<<dim3(96 + 1024), 192, 0, stream>>>(x4, C4, cpart, xpart);
    finalize_expand<<<dim3(8, 128),    256, 0, stream>>>(xpart, cpart, (float4*)d_out);
}